// Round 5
// baseline (349.869 us; speedup 1.0000x reference)
//
#include <hip/hip_runtime.h>

// LoRALinear: out[8192,4096] = x @ W.T + 2.0*(x@A.T)@B.T = x @ (W + 2*B@A).T
// One bf16 MFMA GEMM, 256x256 tile, 8 waves, 4 phases/K-tile with 1-phase
// fragment LOOKAHEAD (reads of phase p feed phase p+1 -> LDS drains under
// MFMA), counted vmcnt (bare asm, no "memory" clobber), 1 barrier/phase.

#define N_ROWS 8192
#define K_DIM  4096
#define N_COLS 4096
#define RANK   16
#define BK     64
#define NT     (K_DIM / BK)   // 64 K-tiles

typedef __bf16 bf16x8 __attribute__((ext_vector_type(8)));
typedef float  f32x4  __attribute__((ext_vector_type(4)));

__device__ __forceinline__ unsigned short f2bf(float f) {
  unsigned int u = __builtin_bit_cast(unsigned int, f);
  u += 0x7FFFu + ((u >> 16) & 1u);   // RNE
  return (unsigned short)(u >> 16);
}

// ---------------- conversion kernels ----------------

__global__ __launch_bounds__(256) void conv_x_kernel(const float* __restrict__ x,
                                                     unsigned short* __restrict__ xb) {
  size_t idx = (size_t)blockIdx.x * blockDim.x + threadIdx.x;
  const float4 v = *reinterpret_cast<const float4*>(x + idx * 4);
  ushort4 r;
  r.x = f2bf(v.x); r.y = f2bf(v.y); r.z = f2bf(v.z); r.w = f2bf(v.w);
  *reinterpret_cast<ushort4*>(xb + idx * 4) = r;
}

__global__ __launch_bounds__(256) void make_weff_kernel(const float* __restrict__ w,
                                                        const float* __restrict__ A,
                                                        const float* __restrict__ Bm,
                                                        unsigned short* __restrict__ wb) {
  size_t idx = (size_t)blockIdx.x * blockDim.x + threadIdx.x;
  int o  = (int)(idx >> 10);
  int ic = (int)(idx & 1023) << 2;
  const float4 wv = *reinterpret_cast<const float4*>(w + (size_t)o * K_DIM + ic);
  float a0 = wv.x, a1 = wv.y, a2 = wv.z, a3 = wv.w;
  float br[RANK];
#pragma unroll
  for (int r4 = 0; r4 < RANK / 4; ++r4) {
    const float4 bv = *reinterpret_cast<const float4*>(Bm + (size_t)o * RANK + r4 * 4);
    br[r4 * 4 + 0] = bv.x; br[r4 * 4 + 1] = bv.y;
    br[r4 * 4 + 2] = bv.z; br[r4 * 4 + 3] = bv.w;
  }
#pragma unroll
  for (int r = 0; r < RANK; ++r) {
    const float4 av = *reinterpret_cast<const float4*>(A + (size_t)r * K_DIM + ic);
    float b2 = br[r] * 2.0f;
    a0 += b2 * av.x; a1 += b2 * av.y; a2 += b2 * av.z; a3 += b2 * av.w;
  }
  ushort4 rr;
  rr.x = f2bf(a0); rr.y = f2bf(a1); rr.z = f2bf(a2); rr.w = f2bf(a3);
  *reinterpret_cast<ushort4*>(wb + (size_t)o * K_DIM + ic) = rr;
}

// ---------------- GEMM ----------------
// LDS: A [buf][half][128 rows][64 k] bf16 at 0..64K; B same at 64K..128K.
// XOR swizzle within a half (16B granules): phys = logical ^ (row&7); staged
// via pre-swizzled global source (linear gload_lds dest), read w/ matching XOR.
// Frags: aE=A0(mf0-3), aO=A1(mf4-7), bE=B0(nf0-1, parity[2]), bO=B1(nf2-3).
// Phase p issues reads consumed in phase p+1; MFMA uses reads from p-1:
//  ph1: rd B1(t)[c];       stage A0,B0,B1(t+1)->n; MFMA aE*bE[PC]; vmcnt(6) bar
//  ph2: rd A1(t)[c];       stage A1(t+1)->n;       MFMA aE*bO;     vmcnt(6) bar
//  ph3: rd A0(t+1)[n]->aE;                         MFMA aO*bO;     vmcnt(4) bar
//  ph4: rd B0(t+1)[n]->bE[PN];                     MFMA aO*bE[PC]; vmcnt(2) bar

__device__ __forceinline__ void gload_lds16(const void* g, void* l) {
  __builtin_amdgcn_global_load_lds(
      (__attribute__((address_space(1))) void*)g,
      (__attribute__((address_space(3))) void*)l, 16, 0, 0);
}

__global__ __launch_bounds__(512, 1) void gemm_bf16_look(
    const unsigned short* __restrict__ xb, const unsigned short* __restrict__ wb,
    float* __restrict__ out) {
  __shared__ __align__(16) char smem[131072];

  const int t  = threadIdx.x;
  const int l  = t & 63;
  const int wv = t >> 6;
  const int lr = l & 15;
  const int lk = l >> 4;
  const int wr = wv >> 2;     // 0..1
  const int wc = wv & 3;      // 0..3

  // XCD-aware bijective swizzle: 512 blocks % 8 == 0
  const int bid  = blockIdx.x;
  const int sbid = (bid & 7) * 64 + (bid >> 3);
  const int bm   = sbid >> 4;   // 0..31
  const int bn   = sbid & 15;   // 0..15

  // staging: thread t -> row t>>3 (0..63), swizzled col granule
  const int srow = t >> 3;
  const int scol = ((t & 7) ^ ((t >> 3) & 7)) << 3;         // elements
  const unsigned short* gA = xb + (size_t)(bm * 256 + srow) * K_DIM + scol;
  const unsigned short* gB = wb + (size_t)(bn * 256 + srow) * K_DIM + scol;
  char* ldsA = smem + t * 16;
  char* ldsB = smem + 65536 + t * 16;

#define STG_A(hh, SRC, NB) do {                                                 \
    const unsigned short* _g = (SRC) + (size_t)((hh) * 128) * K_DIM;            \
    char* _l = ldsA + (NB) + (hh) * 16384;                                      \
    gload_lds16(_g, _l);                                                        \
    gload_lds16(_g + (size_t)64 * K_DIM, _l + 8192);                            \
  } while (0)
#define STG_B(hh, SRC, NB) do {                                                 \
    const unsigned short* _g = (SRC) + (size_t)((hh) * 128) * K_DIM;            \
    char* _l = ldsB + (NB) + (hh) * 16384;                                      \
    gload_lds16(_g, _l);                                                        \
    gload_lds16(_g + (size_t)64 * K_DIM, _l + 8192);                            \
  } while (0)

  // fragment LDS addressing (read-side XOR matches staged swizzle)
  const int g0   = (lk ^ (lr & 7)) << 4;
  const int g1   = ((lk + 4) ^ (lr & 7)) << 4;
  const int aoff = (wr * 16 + lr) * 128;
  const int boff = (wc * 16 + lr) * 128;

  bf16x8 aE[8], aO[8], bO[4], bE[2][4];
  f32x4 acc[8][4];
#pragma unroll
  for (int m = 0; m < 8; ++m)
#pragma unroll
    for (int n = 0; n < 4; ++n)
      acc[m][n] = (f32x4){0.f, 0.f, 0.f, 0.f};

#define RD_A(DST, BASE) do {                                                    \
    _Pragma("unroll")                                                           \
    for (int m = 0; m < 4; ++m) {                                               \
      DST[2 * m + 0] = *(const bf16x8*)(smem + (BASE) + m * 4096 + aoff + g0);  \
      DST[2 * m + 1] = *(const bf16x8*)(smem + (BASE) + m * 4096 + aoff + g1);  \
    }                                                                           \
  } while (0)
#define RD_B(DST, BASE) do {                                                    \
    _Pragma("unroll")                                                           \
    for (int n = 0; n < 2; ++n) {                                               \
      DST[2 * n + 0] = *(const bf16x8*)(smem + 65536 + (BASE) + n * 8192 + boff + g0); \
      DST[2 * n + 1] = *(const bf16x8*)(smem + 65536 + (BASE) + n * 8192 + boff + g1); \
    }                                                                           \
  } while (0)

#define MFMA_Q(MB, AF, NB0, BF) do {                                            \
    _Pragma("unroll")                                                           \
    for (int mi = 0; mi < 4; ++mi)                                              \
      _Pragma("unroll")                                                         \
      for (int ni = 0; ni < 2; ++ni)                                            \
        _Pragma("unroll")                                                       \
        for (int kk = 0; kk < 2; ++kk)                                          \
          acc[(MB) + mi][(NB0) + ni] = __builtin_amdgcn_mfma_f32_16x16x32_bf16( \
              AF[mi * 2 + kk], BF[ni * 2 + kk], acc[(MB) + mi][(NB0) + ni], 0, 0, 0); \
  } while (0)

// phase end: counted vmcnt (bare asm -- no memory clobber!) then barrier
#define PH_END(VM) do {                                                         \
    __builtin_amdgcn_sched_barrier(0);                                          \
    asm volatile("s_waitcnt vmcnt(" #VM ")");                                   \
    __builtin_amdgcn_s_barrier();                                               \
    __builtin_amdgcn_sched_barrier(0);                                          \
  } while (0)

#define TILE(CB, NB, PC, PN, T) do {                                            \
    const int _tk = ((T) + 1 < NT) ? (T) + 1 : NT - 1;                          \
    const unsigned short* _sA = gA + (size_t)_tk * BK;                          \
    const unsigned short* _sB = gB + (size_t)_tk * BK;                          \
    /* ph1: MFMA aE*bE[PC]; rd bO=B1(t); stage A0,B0,B1(t+1) */                 \
    RD_B(bO, (CB) + 16384);                                                     \
    STG_A(0, _sA, NB); STG_B(0, _sB, NB); STG_B(1, _sB, NB);                    \
    __builtin_amdgcn_sched_barrier(0);                                          \
    __builtin_amdgcn_s_setprio(1); MFMA_Q(0, aE, 0, bE[PC]);                    \
    __builtin_amdgcn_s_setprio(0);                                              \
    PH_END(6);                                                                  \
    /* ph2: MFMA aE*bO; rd aO=A1(t); stage A1(t+1) */                           \
    RD_A(aO, (CB) + 16384);                                                     \
    STG_A(1, _sA, NB);                                                          \
    __builtin_amdgcn_sched_barrier(0);                                          \
    __builtin_amdgcn_s_setprio(1); MFMA_Q(0, aE, 2, bO);                        \
    __builtin_amdgcn_s_setprio(0);                                              \
    PH_END(6);                                                                  \
    /* ph3: MFMA aO*bO; rd aE=A0(t+1) */                                        \
    RD_A(aE, (NB));                                                             \
    __builtin_amdgcn_sched_barrier(0);                                          \
    __builtin_amdgcn_s_setprio(1); MFMA_Q(4, aO, 2, bO);                        \
    __builtin_amdgcn_s_setprio(0);                                              \
    PH_END(4);                                                                  \
    /* ph4: MFMA aO*bE[PC]; rd bE[PN]=B0(t+1) */                                \
    RD_B(bE[PN], (NB));                                                         \
    __builtin_amdgcn_sched_barrier(0);                                          \
    __builtin_amdgcn_s_setprio(1); MFMA_Q(4, aO, 0, bE[PC]);                    \
    __builtin_amdgcn_s_setprio(0);                                              \
    PH_END(2);                                                                  \
  } while (0)

  // ---- prologue: stage tile0 -> buf0; drain; pre-read aE=A0(0), bE[0]=B0(0)
  STG_A(0, gA, 0); STG_A(1, gA, 0); STG_B(0, gB, 0); STG_B(1, gB, 0);
  __builtin_amdgcn_sched_barrier(0);
  asm volatile("s_waitcnt vmcnt(0)");
  __builtin_amdgcn_s_barrier();
  __builtin_amdgcn_sched_barrier(0);
  RD_A(aE, 0);
  RD_B(bE[0], 0);

#pragma nounroll
  for (int u = 0; u < NT / 2; ++u) {
    TILE(0, 32768, 0, 1, 2 * u);
    TILE(32768, 0, 1, 0, 2 * u + 1);
  }

  asm volatile("s_waitcnt vmcnt(0)");

  // ---- epilogue: C/D layout col=lane&15, row=(lane>>4)*4+j ----
  const int orow = bm * 256 + wr * 16 + lk * 4;
  const int ocol = bn * 256 + wc * 16 + lr;
#pragma unroll
  for (int mf = 0; mf < 8; ++mf)
#pragma unroll
    for (int nf = 0; nf < 4; ++nf)
#pragma unroll
      for (int j = 0; j < 4; ++j)
        out[(size_t)(orow + mf * 32 + j) * N_COLS + (ocol + nf * 64)] = acc[mf][nf][j];

#undef STG_A
#undef STG_B
#undef RD_A
#undef RD_B
#undef MFMA_Q
#undef PH_END
#undef TILE
}

// ---------------- exact fp32 fallback (ws too small) ----------------

__global__ __launch_bounds__(256) void fallback_kernel(const float* __restrict__ x,
                                                       const float* __restrict__ w,
                                                       const float* __restrict__ A,
                                                       const float* __restrict__ Bm,
                                                       float* __restrict__ out) {
  const int o    = blockIdx.x * 256 + threadIdx.x;
  const int nrow = blockIdx.y;
  float bro[RANK];
#pragma unroll
  for (int r = 0; r < RANK; ++r) bro[r] = Bm[(size_t)o * RANK + r] * 2.0f;
  float bacc = 0.f;
  float tacc[RANK];
#pragma unroll
  for (int r = 0; r < RANK; ++r) tacc[r] = 0.f;
  for (int k = 0; k < K_DIM; ++k) {
    float xv = x[(size_t)nrow * K_DIM + k];
    bacc += xv * w[(size_t)o * K_DIM + k];
#pragma unroll
    for (int r = 0; r < RANK; ++r) tacc[r] += xv * A[(size_t)r * K_DIM + k];
  }
  float res = bacc;
#pragma unroll
  for (int r = 0; r < RANK; ++r) res += bro[r] * tacc[r];
  out[(size_t)nrow * N_COLS + o] = res;
}

// ---------------- launch ----------------

extern "C" void kernel_launch(void* const* d_in, const int* in_sizes, int n_in,
                              void* d_out, int out_size, void* d_ws, size_t ws_size,
                              hipStream_t stream) {
  const float* x  = (const float*)d_in[0];
  const float* w  = (const float*)d_in[1];
  const float* A  = (const float*)d_in[2];
  const float* Bm = (const float*)d_in[3];
  float* out = (float*)d_out;

  const size_t need = ((size_t)N_ROWS * K_DIM + (size_t)N_COLS * K_DIM) * sizeof(unsigned short);
  if (ws_size < need) {
    dim3 grid(N_COLS / 256, N_ROWS);
    fallback_kernel<<<grid, 256, 0, stream>>>(x, w, A, Bm, out);
    return;
  }

  unsigned short* xb = (unsigned short*)d_ws;
  unsigned short* wb = xb + (size_t)N_ROWS * K_DIM;

  conv_x_kernel<<<(N_ROWS * K_DIM / 4) / 256, 256, 0, stream>>>(x, xb);
  make_weff_kernel<<<(N_COLS * K_DIM / 4) / 256, 256, 0, stream>>>(w, A, Bm, wb);

  const int grid_gemm = (N_ROWS / 256) * (N_COLS / 256);   // 512
  gemm_bf16_look<<<grid_gemm, 512, 0, stream>>>(xb, wb, out);
}

// Round 7
// 314.074 us; speedup vs baseline: 1.1140x; 1.1140x over previous
//
#include <hip/hip_runtime.h>

// LoRALinear: out[8192,4096] = x @ W.T + 2.0*(x@A.T)@B.T = x @ (W + 2*B@A).T
// One bf16 MFMA GEMM, 256x256 tile, 8 waves, 4 phases/K-tile (phase-local
// consume, R2-proven loose stage slack, vmcnt(4) once per tile), B0 held in
// regs across the tile (24 ds_read_b128/wave/tile), STAGE-first ordering.

#define N_ROWS 8192
#define K_DIM  4096
#define N_COLS 4096
#define RANK   16
#define BK     64
#define NT     (K_DIM / BK)   // 64 K-tiles

#define XBLK ((N_ROWS * K_DIM / 4) / 256)   // 32768 blocks for x->bf16
#define WBLK ((N_COLS * K_DIM / 4) / 256)   // 16384 blocks for W_eff->bf16

typedef __bf16 bf16x8 __attribute__((ext_vector_type(8)));
typedef float  f32x4  __attribute__((ext_vector_type(4)));

__device__ __forceinline__ unsigned short f2bf(float f) {
  unsigned int u = __builtin_bit_cast(unsigned int, f);
  u += 0x7FFFu + ((u >> 16) & 1u);   // RNE
  return (unsigned short)(u >> 16);
}

// ---------------- fused conversion kernel ----------------
// blocks [0, XBLK):          x (f32) -> xb (bf16), 4 elems/thread
// blocks [XBLK, XBLK+WBLK):  wb = bf16(W + 2*B@A), 4 elems/thread

__global__ __launch_bounds__(256) void prep_kernel(const float* __restrict__ x,
                                                   const float* __restrict__ w,
                                                   const float* __restrict__ A,
                                                   const float* __restrict__ Bm,
                                                   unsigned short* __restrict__ xb,
                                                   unsigned short* __restrict__ wb) {
  const int b = blockIdx.x;
  if (b < XBLK) {
    size_t idx = (size_t)b * 256 + threadIdx.x;
    const float4 v = *reinterpret_cast<const float4*>(x + idx * 4);
    ushort4 r;
    r.x = f2bf(v.x); r.y = f2bf(v.y); r.z = f2bf(v.z); r.w = f2bf(v.w);
    *reinterpret_cast<ushort4*>(xb + idx * 4) = r;
  } else {
    size_t idx = (size_t)(b - XBLK) * 256 + threadIdx.x;
    int o  = (int)(idx >> 10);
    int ic = (int)(idx & 1023) << 2;
    const float4 wv = *reinterpret_cast<const float4*>(w + (size_t)o * K_DIM + ic);
    float a0 = wv.x, a1 = wv.y, a2 = wv.z, a3 = wv.w;
    float br[RANK];
#pragma unroll
    for (int r4 = 0; r4 < RANK / 4; ++r4) {
      const float4 bv = *reinterpret_cast<const float4*>(Bm + (size_t)o * RANK + r4 * 4);
      br[r4 * 4 + 0] = bv.x; br[r4 * 4 + 1] = bv.y;
      br[r4 * 4 + 2] = bv.z; br[r4 * 4 + 3] = bv.w;
    }
#pragma unroll
    for (int r = 0; r < RANK; ++r) {
      const float4 av = *reinterpret_cast<const float4*>(A + (size_t)r * K_DIM + ic);
      float b2 = br[r] * 2.0f;
      a0 += b2 * av.x; a1 += b2 * av.y; a2 += b2 * av.z; a3 += b2 * av.w;
    }
    ushort4 rr;
    rr.x = f2bf(a0); rr.y = f2bf(a1); rr.z = f2bf(a2); rr.w = f2bf(a3);
    *reinterpret_cast<ushort4*>(wb + (size_t)o * K_DIM + ic) = rr;
  }
}

// ---------------- GEMM ----------------
// LDS: A [buf][half][128 rows][64 k] bf16 at 0..64K; B same at 64K..128K.
// XOR swizzle within a half (16B granules): phys = logical ^ (row&7); staged
// via pre-swizzled global source (linear gload_lds dest), read w/ matching XOR.
// Tile t (cbuf c, nbuf n) — phase-local consume; stages (R2-proven stream):
//  ph1: STG A1(t+1)->n; rd A0,B0(t)[c] (12); lgkm(8); bar lgkm0; MFMA mf0-3 x nf0-1; bar
//  ph2: STG B0(t+1)->n; rd B1(t)[c] (4);     bar lgkm0; MFMA mf0-3 x nf2-3; bar
//  ph3: STG A0(t+2)->c; rd A1(t)[c] (8);     bar lgkm0; MFMA mf4-7 x nf2-3; bar
//  ph4: STG B1(t+2)->c; (B0 held in regs);   bar;       MFMA mf4-7 x nf0-1; vmcnt(4) bar

__device__ __forceinline__ void gload_lds16(const void* g, void* l) {
  __builtin_amdgcn_global_load_lds(
      (__attribute__((address_space(1))) void*)g,
      (__attribute__((address_space(3))) void*)l, 16, 0, 0);
}

__global__ __launch_bounds__(512, 1) void gemm_bf16_r7(
    const unsigned short* __restrict__ xb, const unsigned short* __restrict__ wb,
    float* __restrict__ out) {
  __shared__ __align__(16) char smem[131072];

  const int t  = threadIdx.x;
  const int l  = t & 63;
  const int wv = t >> 6;
  const int lr = l & 15;
  const int lk = l >> 4;
  const int wr = wv >> 2;     // 0..1
  const int wc = wv & 3;      // 0..3

  // XCD-aware bijective swizzle: 512 blocks % 8 == 0
  const int bid  = blockIdx.x;
  const int sbid = (bid & 7) * 64 + (bid >> 3);
  const int bm   = sbid >> 4;   // 0..31
  const int bn   = sbid & 15;   // 0..15

  // staging: thread t -> row t>>3 (0..63), swizzled col granule
  const int srow = t >> 3;
  const int scol = ((t & 7) ^ ((t >> 3) & 7)) << 3;         // elements
  const unsigned short* gA = xb + (size_t)(bm * 256 + srow) * K_DIM + scol;
  const unsigned short* gB = wb + (size_t)(bn * 256 + srow) * K_DIM + scol;
  char* ldsA = smem + t * 16;
  char* ldsB = smem + 65536 + t * 16;

#define STG_A(hh, SRC, NB) do {                                                 \
    const unsigned short* _g = (SRC) + (size_t)((hh) * 128) * K_DIM;            \
    char* _l = ldsA + (NB) + (hh) * 16384;                                      \
    gload_lds16(_g, _l);                                                        \
    gload_lds16(_g + (size_t)64 * K_DIM, _l + 8192);                            \
  } while (0)
#define STG_B(hh, SRC, NB) do {                                                 \
    const unsigned short* _g = (SRC) + (size_t)((hh) * 128) * K_DIM;            \
    char* _l = ldsB + (NB) + (hh) * 16384;                                      \
    gload_lds16(_g, _l);                                                        \
    gload_lds16(_g + (size_t)64 * K_DIM, _l + 8192);                            \
  } while (0)

  // fragment LDS addressing (read-side XOR matches staged swizzle)
  const int g0   = (lk ^ (lr & 7)) << 4;
  const int g1   = ((lk + 4) ^ (lr & 7)) << 4;
  const int aoff = (wr * 16 + lr) * 128;
  const int boff = (wc * 16 + lr) * 128;

  bf16x8 aF[8];      // current A half (A0 in ph1-2, A1 in ph3-4)
  bf16x8 bE[4];      // B0(t): read ph1, HELD through ph4 (kills re-read)
  bf16x8 bO[4];      // B1(t): read ph2, used ph2-ph3
  f32x4 acc[8][4];
#pragma unroll
  for (int m = 0; m < 8; ++m)
#pragma unroll
    for (int n = 0; n < 4; ++n)
      acc[m][n] = (f32x4){0.f, 0.f, 0.f, 0.f};

#define RD_A(BASE) do {                                                         \
    _Pragma("unroll")                                                           \
    for (int m = 0; m < 4; ++m) {                                               \
      aF[2 * m + 0] = *(const bf16x8*)(smem + (BASE) + m * 4096 + aoff + g0);   \
      aF[2 * m + 1] = *(const bf16x8*)(smem + (BASE) + m * 4096 + aoff + g1);   \
    }                                                                           \
  } while (0)
#define RD_B(DST, BASE) do {                                                    \
    _Pragma("unroll")                                                           \
    for (int n = 0; n < 2; ++n) {                                               \
      DST[2 * n + 0] = *(const bf16x8*)(smem + 65536 + (BASE) + n * 8192 + boff + g0); \
      DST[2 * n + 1] = *(const bf16x8*)(smem + 65536 + (BASE) + n * 8192 + boff + g1); \
    }                                                                           \
  } while (0)

#define MFMA_Q(MB, NB0, BF) do {                                                \
    _Pragma("unroll")                                                           \
    for (int mi = 0; mi < 4; ++mi)                                              \
      _Pragma("unroll")                                                         \
      for (int ni = 0; ni < 2; ++ni)                                            \
        _Pragma("unroll")                                                       \
        for (int kk = 0; kk < 2; ++kk)                                          \
          acc[(MB) + mi][(NB0) + ni] = __builtin_amdgcn_mfma_f32_16x16x32_bf16( \
              aF[mi * 2 + kk], BF[ni * 2 + kk], acc[(MB) + mi][(NB0) + ni], 0, 0, 0); \
  } while (0)

#define PRE_LG() do {                                                           \
    __builtin_amdgcn_sched_barrier(0);                                          \
    __builtin_amdgcn_s_barrier();                                               \
    asm volatile("s_waitcnt lgkmcnt(0)");                                       \
    __builtin_amdgcn_sched_barrier(0);                                          \
    __builtin_amdgcn_s_setprio(1);                                              \
  } while (0)
#define PRE_NOLG() do {                                                         \
    __builtin_amdgcn_sched_barrier(0);                                          \
    __builtin_amdgcn_s_barrier();                                               \
    __builtin_amdgcn_sched_barrier(0);                                          \
    __builtin_amdgcn_s_setprio(1);                                              \
  } while (0)
#define POST() do {                                                             \
    __builtin_amdgcn_s_setprio(0);                                              \
    __builtin_amdgcn_sched_barrier(0);                                          \
    __builtin_amdgcn_s_barrier();                                               \
    __builtin_amdgcn_sched_barrier(0);                                          \
  } while (0)
#define POST_VM4() do {                                                         \
    __builtin_amdgcn_s_setprio(0);                                              \
    __builtin_amdgcn_sched_barrier(0);                                          \
    asm volatile("s_waitcnt vmcnt(4)");                                         \
    __builtin_amdgcn_s_barrier();                                               \
    __builtin_amdgcn_sched_barrier(0);                                          \
  } while (0)

#define TILE(CB, NB, T) do {                                                    \
    const int _t1 = ((T) + 1 < NT) ? (T) + 1 : NT - 1;                          \
    const int _t2 = ((T) + 2 < NT) ? (T) + 2 : NT - 1;                          \
    const unsigned short* _sA1 = gA + (size_t)_t1 * BK;                         \
    const unsigned short* _sB1 = gB + (size_t)_t1 * BK;                         \
    const unsigned short* _sA2 = gA + (size_t)_t2 * BK;                         \
    const unsigned short* _sB2 = gB + (size_t)_t2 * BK;                         \
    /* ph1: stage A1(t+1)->n; rd A0,B0(t); MFMA mf0-3 x nf0-1 */                \
    STG_A(1, _sA1, NB);                                                         \
    RD_A((CB)); RD_B(bE, (CB));                                                 \
    asm volatile("s_waitcnt lgkmcnt(8)");                                       \
    PRE_LG(); MFMA_Q(0, 0, bE); POST();                                         \
    /* ph2: stage B0(t+1)->n; rd B1(t); MFMA mf0-3 x nf2-3 */                   \
    STG_B(0, _sB1, NB);                                                         \
    RD_B(bO, (CB) + 16384);                                                     \
    PRE_LG(); MFMA_Q(0, 2, bO); POST();                                         \
    /* ph3: stage A0(t+2)->c; rd A1(t); MFMA mf4-7 x nf2-3 */                   \
    STG_A(0, _sA2, CB);                                                         \
    RD_A((CB) + 16384);                                                         \
    PRE_LG(); MFMA_Q(4, 2, bO); POST();                                         \
    /* ph4: stage B1(t+2)->c; B0 from regs; MFMA mf4-7 x nf0-1; vmcnt(4) */     \
    STG_B(1, _sB2, CB);                                                         \
    PRE_NOLG(); MFMA_Q(4, 0, bE); POST_VM4();                                   \
  } while (0)

  // ---- prologue: stage tile0 -> buf0 (8) + A0(1),B1(1) -> buf1 (4); vmcnt(4)
  STG_A(0, gA, 0); STG_A(1, gA, 0); STG_B(0, gB, 0); STG_B(1, gB, 0);
  {
    const unsigned short* _pA1 = gA + (size_t)BK;
    const unsigned short* _pB1 = gB + (size_t)BK;
    STG_A(0, _pA1, 32768);
    STG_B(1, _pB1, 32768);
  }
  __builtin_amdgcn_sched_barrier(0);
  asm volatile("s_waitcnt vmcnt(4)");
  __builtin_amdgcn_s_barrier();
  __builtin_amdgcn_sched_barrier(0);

#pragma nounroll
  for (int u = 0; u < NT / 2; ++u) {
    TILE(0, 32768, 2 * u);
    TILE(32768, 0, 2 * u + 1);
  }

  // ---- epilogue: C/D layout col=lane&15, row=(lane>>4)*4+j ----
  const int orow = bm * 256 + wr * 16 + lk * 4;
  const int ocol = bn * 256 + wc * 16 + lr;
#pragma unroll
  for (int mf = 0; mf < 8; ++mf)
#pragma unroll
    for (int nf = 0; nf < 4; ++nf)
#pragma unroll
      for (int j = 0; j < 4; ++j)
        out[(size_t)(orow + mf * 32 + j) * N_COLS + (ocol + nf * 64)] = acc[mf][nf][j];

#undef STG_A
#undef STG_B
#undef RD_A
#undef RD_B
#undef MFMA_Q
#undef PRE_LG
#undef PRE_NOLG
#undef POST
#undef POST_VM4
#undef TILE
}

// ---------------- exact fp32 fallback (ws too small) ----------------

__global__ __launch_bounds__(256) void fallback_kernel(const float* __restrict__ x,
                                                       const float* __restrict__ w,
                                                       const float* __restrict__ A,
                                                       const float* __restrict__ Bm,
                                                       float* __restrict__ out) {
  const int o    = blockIdx.x * 256 + threadIdx.x;
  const int nrow = blockIdx.y;
  float bro[RANK];
#pragma unroll
  for (int r = 0; r < RANK; ++r) bro[r] = Bm[(size_t)o * RANK + r] * 2.0f;
  float bacc = 0.f;
  float tacc[RANK];
#pragma unroll
  for (int r = 0; r < RANK; ++r) tacc[r] = 0.f;
  for (int k = 0; k < K_DIM; ++k) {
    float xv = x[(size_t)nrow * K_DIM + k];
    bacc += xv * w[(size_t)o * K_DIM + k];
#pragma unroll
    for (int r = 0; r < RANK; ++r) tacc[r] += xv * A[(size_t)r * K_DIM + k];
  }
  float res = bacc;
#pragma unroll
  for (int r = 0; r < RANK; ++r) res += bro[r] * tacc[r];
  out[(size_t)nrow * N_COLS + o] = res;
}

// ---------------- launch ----------------

extern "C" void kernel_launch(void* const* d_in, const int* in_sizes, int n_in,
                              void* d_out, int out_size, void* d_ws, size_t ws_size,
                              hipStream_t stream) {
  const float* x  = (const float*)d_in[0];
  const float* w  = (const float*)d_in[1];
  const float* A  = (const float*)d_in[2];
  const float* Bm = (const float*)d_in[3];
  float* out = (float*)d_out;

  const size_t need = ((size_t)N_ROWS * K_DIM + (size_t)N_COLS * K_DIM) * sizeof(unsigned short);
  if (ws_size < need) {
    dim3 grid(N_COLS / 256, N_ROWS);
    fallback_kernel<<<grid, 256, 0, stream>>>(x, w, A, Bm, out);
    return;
  }

  unsigned short* xb = (unsigned short*)d_ws;
  unsigned short* wb = xb + (size_t)N_ROWS * K_DIM;

  prep_kernel<<<XBLK + WBLK, 256, 0, stream>>>(x, w, A, Bm, xb, wb);

  const int grid_gemm = (N_ROWS / 256) * (N_COLS / 256);   // 512
  gemm_bf16_r7<<<grid_gemm, 512, 0, stream>>>(xb, wb, out);
}

// Round 8
// 309.970 us; speedup vs baseline: 1.1287x; 1.0132x over previous
//
#include <hip/hip_runtime.h>

// LoRALinear: out[8192,4096] = x @ W.T + 2.0*(x@A.T)@B.T = x @ (W + 2*B@A).T
// One bf16 MFMA GEMM, 256x256 tile, 8 waves, ONE barrier per K-tile:
// {stage(t+1) -> free compiler-scheduled reads+MFMA -> lgkm(0) vmcnt(0) bar}.
// Wave skew + counted lgkmcnt overlap LDS-read and MFMA pipes (m97 property).

#define N_ROWS 8192
#define K_DIM  4096
#define N_COLS 4096
#define RANK   16
#define BK     64
#define NT     (K_DIM / BK)   // 64 K-tiles

#define XBLK ((N_ROWS * K_DIM / 4) / 256)   // 32768 blocks for x->bf16
#define WBLK ((N_COLS * K_DIM / 4) / 256)   // 16384 blocks for W_eff->bf16

typedef __bf16 bf16x8 __attribute__((ext_vector_type(8)));
typedef float  f32x4  __attribute__((ext_vector_type(4)));

__device__ __forceinline__ unsigned short f2bf(float f) {
  unsigned int u = __builtin_bit_cast(unsigned int, f);
  u += 0x7FFFu + ((u >> 16) & 1u);   // RNE
  return (unsigned short)(u >> 16);
}

// ---------------- fused conversion kernel ----------------

__global__ __launch_bounds__(256) void prep_kernel(const float* __restrict__ x,
                                                   const float* __restrict__ w,
                                                   const float* __restrict__ A,
                                                   const float* __restrict__ Bm,
                                                   unsigned short* __restrict__ xb,
                                                   unsigned short* __restrict__ wb) {
  const int b = blockIdx.x;
  if (b < XBLK) {
    size_t idx = (size_t)b * 256 + threadIdx.x;
    const float4 v = *reinterpret_cast<const float4*>(x + idx * 4);
    ushort4 r;
    r.x = f2bf(v.x); r.y = f2bf(v.y); r.z = f2bf(v.z); r.w = f2bf(v.w);
    *reinterpret_cast<ushort4*>(xb + idx * 4) = r;
  } else {
    size_t idx = (size_t)(b - XBLK) * 256 + threadIdx.x;
    int o  = (int)(idx >> 10);
    int ic = (int)(idx & 1023) << 2;
    const float4 wv = *reinterpret_cast<const float4*>(w + (size_t)o * K_DIM + ic);
    float a0 = wv.x, a1 = wv.y, a2 = wv.z, a3 = wv.w;
    float br[RANK];
#pragma unroll
    for (int r4 = 0; r4 < RANK / 4; ++r4) {
      const float4 bv = *reinterpret_cast<const float4*>(Bm + (size_t)o * RANK + r4 * 4);
      br[r4 * 4 + 0] = bv.x; br[r4 * 4 + 1] = bv.y;
      br[r4 * 4 + 2] = bv.z; br[r4 * 4 + 3] = bv.w;
    }
#pragma unroll
    for (int r = 0; r < RANK; ++r) {
      const float4 av = *reinterpret_cast<const float4*>(A + (size_t)r * K_DIM + ic);
      float b2 = br[r] * 2.0f;
      a0 += b2 * av.x; a1 += b2 * av.y; a2 += b2 * av.z; a3 += b2 * av.w;
    }
    ushort4 rr;
    rr.x = f2bf(a0); rr.y = f2bf(a1); rr.z = f2bf(a2); rr.w = f2bf(a3);
    *reinterpret_cast<ushort4*>(wb + (size_t)o * K_DIM + ic) = rr;
  }
}

// ---------------- GEMM ----------------
// LDS: A [buf][half][128 rows][64 k] bf16 at 0..64K; B same at 64K..128K.
// XOR swizzle within a half (16B granules): phys = logical ^ (row&7); staged
// via pre-swizzled global source (linear gload_lds dest), read w/ matching XOR.
// Per tile t (cbuf c, nbuf n):
//   stage A0,A1,B0,B1(t+1)->n (8 gloads, issue-first)
//   [compiler-scheduled] 24 ds_read_b128 from c + 64 MFMA, counted lgkmcnt
//   lgkm(0); vmcnt(0); s_barrier           <- the ONLY barrier per tile

__device__ __forceinline__ void gload_lds16(const void* g, void* l) {
  __builtin_amdgcn_global_load_lds(
      (__attribute__((address_space(1))) void*)g,
      (__attribute__((address_space(3))) void*)l, 16, 0, 0);
}

__global__ __launch_bounds__(512, 1) void gemm_bf16_r8(
    const unsigned short* __restrict__ xb, const unsigned short* __restrict__ wb,
    float* __restrict__ out) {
  __shared__ __align__(16) char smem[131072];

  const int t  = threadIdx.x;
  const int l  = t & 63;
  const int wv = t >> 6;
  const int lr = l & 15;
  const int lk = l >> 4;
  const int wr = wv >> 2;     // 0..1
  const int wc = wv & 3;      // 0..3

  // XCD-aware bijective swizzle: 512 blocks % 8 == 0
  const int bid  = blockIdx.x;
  const int sbid = (bid & 7) * 64 + (bid >> 3);
  const int bm   = sbid >> 4;   // 0..31
  const int bn   = sbid & 15;   // 0..15

  // staging: thread t -> row t>>3 (0..63), swizzled col granule
  const int srow = t >> 3;
  const int scol = ((t & 7) ^ ((t >> 3) & 7)) << 3;         // elements
  const unsigned short* gA = xb + (size_t)(bm * 256 + srow) * K_DIM + scol;
  const unsigned short* gB = wb + (size_t)(bn * 256 + srow) * K_DIM + scol;
  char* ldsA = smem + t * 16;
  char* ldsB = smem + 65536 + t * 16;

#define STG_A(hh, SRC, NB) do {                                                 \
    const unsigned short* _g = (SRC) + (size_t)((hh) * 128) * K_DIM;            \
    char* _l = ldsA + (NB) + (hh) * 16384;                                      \
    gload_lds16(_g, _l);                                                        \
    gload_lds16(_g + (size_t)64 * K_DIM, _l + 8192);                            \
  } while (0)
#define STG_B(hh, SRC, NB) do {                                                 \
    const unsigned short* _g = (SRC) + (size_t)((hh) * 128) * K_DIM;            \
    char* _l = ldsB + (NB) + (hh) * 16384;                                      \
    gload_lds16(_g, _l);                                                        \
    gload_lds16(_g + (size_t)64 * K_DIM, _l + 8192);                            \
  } while (0)

  // fragment LDS addressing (read-side XOR matches staged swizzle)
  const int g0   = (lk ^ (lr & 7)) << 4;
  const int g1   = ((lk + 4) ^ (lr & 7)) << 4;
  const int aoff = (wr * 16 + lr) * 128;
  const int boff = (wc * 16 + lr) * 128;

  bf16x8 aF[8];      // current A half (renamed by compiler across halves)
  bf16x8 bE[4];      // B0(t)
  bf16x8 bO[4];      // B1(t)
  f32x4 acc[8][4];
#pragma unroll
  for (int m = 0; m < 8; ++m)
#pragma unroll
    for (int n = 0; n < 4; ++n)
      acc[m][n] = (f32x4){0.f, 0.f, 0.f, 0.f};

#define RD_A(BASE) do {                                                         \
    _Pragma("unroll")                                                           \
    for (int m = 0; m < 4; ++m) {                                               \
      aF[2 * m + 0] = *(const bf16x8*)(smem + (BASE) + m * 4096 + aoff + g0);   \
      aF[2 * m + 1] = *(const bf16x8*)(smem + (BASE) + m * 4096 + aoff + g1);   \
    }                                                                           \
  } while (0)
#define RD_B(DST, BASE) do {                                                    \
    _Pragma("unroll")                                                           \
    for (int n = 0; n < 2; ++n) {                                               \
      DST[2 * n + 0] = *(const bf16x8*)(smem + 65536 + (BASE) + n * 8192 + boff + g0); \
      DST[2 * n + 1] = *(const bf16x8*)(smem + 65536 + (BASE) + n * 8192 + boff + g1); \
    }                                                                           \
  } while (0)

#define MFMA_Q(MB, NB0, BF) do {                                                \
    _Pragma("unroll")                                                           \
    for (int mi = 0; mi < 4; ++mi)                                              \
      _Pragma("unroll")                                                         \
      for (int ni = 0; ni < 2; ++ni)                                            \
        _Pragma("unroll")                                                       \
        for (int kk = 0; kk < 2; ++kk)                                          \
          acc[(MB) + mi][(NB0) + ni] = __builtin_amdgcn_mfma_f32_16x16x32_bf16( \
              aF[mi * 2 + kk], BF[ni * 2 + kk], acc[(MB) + mi][(NB0) + ni], 0, 0, 0); \
  } while (0)

#define TILE(CB, NB, T) do {                                                    \
    const int _t1 = ((T) + 1 < NT) ? (T) + 1 : NT - 1;                          \
    const unsigned short* _sA = gA + (size_t)_t1 * BK;                          \
    const unsigned short* _sB = gB + (size_t)_t1 * BK;                          \
    /* issue-first staging of t+1 into buf n */                                 \
    STG_A(0, _sA, NB); STG_A(1, _sA, NB);                                       \
    STG_B(0, _sB, NB); STG_B(1, _sB, NB);                                       \
    __builtin_amdgcn_sched_barrier(0);                                          \
    /* free interior: compiler interleaves reads & MFMAs w/ counted lgkmcnt */  \
    RD_A((CB));                                                                 \
    RD_B(bE, (CB));                                                             \
    RD_B(bO, (CB) + 16384);                                                     \
    MFMA_Q(0, 0, bE);                                                           \
    MFMA_Q(0, 2, bO);                                                           \
    RD_A((CB) + 16384);                                                         \
    MFMA_Q(4, 0, bE);                                                           \
    MFMA_Q(4, 2, bO);                                                           \
    /* tile-end fence: own reads drained, own stages landed, then barrier */    \
    asm volatile("s_waitcnt lgkmcnt(0)");                                       \
    __builtin_amdgcn_sched_barrier(0);                                          \
    asm volatile("s_waitcnt vmcnt(0)");                                         \
    __builtin_amdgcn_s_barrier();                                               \
    __builtin_amdgcn_sched_barrier(0);                                          \
  } while (0)

  // ---- prologue: stage tile0 -> buf0; drain; barrier ----
  STG_A(0, gA, 0); STG_A(1, gA, 0); STG_B(0, gB, 0); STG_B(1, gB, 0);
  __builtin_amdgcn_sched_barrier(0);
  asm volatile("s_waitcnt vmcnt(0)");
  __builtin_amdgcn_s_barrier();
  __builtin_amdgcn_sched_barrier(0);

#pragma nounroll
  for (int u = 0; u < NT / 2; ++u) {
    TILE(0, 32768, 2 * u);
    TILE(32768, 0, 2 * u + 1);
  }

  // ---- epilogue: C/D layout col=lane&15, row=(lane>>4)*4+j ----
  const int orow = bm * 256 + wr * 16 + lk * 4;
  const int ocol = bn * 256 + wc * 16 + lr;
#pragma unroll
  for (int mf = 0; mf < 8; ++mf)
#pragma unroll
    for (int nf = 0; nf < 4; ++nf)
#pragma unroll
      for (int j = 0; j < 4; ++j)
        out[(size_t)(orow + mf * 32 + j) * N_COLS + (ocol + nf * 64)] = acc[mf][nf][j];

#undef STG_A
#undef STG_B
#undef RD_A
#undef RD_B
#undef MFMA_Q
#undef TILE
}

// ---------------- exact fp32 fallback (ws too small) ----------------

__global__ __launch_bounds__(256) void fallback_kernel(const float* __restrict__ x,
                                                       const float* __restrict__ w,
                                                       const float* __restrict__ A,
                                                       const float* __restrict__ Bm,
                                                       float* __restrict__ out) {
  const int o    = blockIdx.x * 256 + threadIdx.x;
  const int nrow = blockIdx.y;
  float bro[RANK];
#pragma unroll
  for (int r = 0; r < RANK; ++r) bro[r] = Bm[(size_t)o * RANK + r] * 2.0f;
  float bacc = 0.f;
  float tacc[RANK];
#pragma unroll
  for (int r = 0; r < RANK; ++r) tacc[r] = 0.f;
  for (int k = 0; k < K_DIM; ++k) {
    float xv = x[(size_t)nrow * K_DIM + k];
    bacc += xv * w[(size_t)o * K_DIM + k];
#pragma unroll
    for (int r = 0; r < RANK; ++r) tacc[r] += xv * A[(size_t)r * K_DIM + k];
  }
  float res = bacc;
#pragma unroll
  for (int r = 0; r < RANK; ++r) res += bro[r] * tacc[r];
  out[(size_t)nrow * N_COLS + o] = res;
}

// ---------------- launch ----------------

extern "C" void kernel_launch(void* const* d_in, const int* in_sizes, int n_in,
                              void* d_out, int out_size, void* d_ws, size_t ws_size,
                              hipStream_t stream) {
  const float* x  = (const float*)d_in[0];
  const float* w  = (const float*)d_in[1];
  const float* A  = (const float*)d_in[2];
  const float* Bm = (const float*)d_in[3];
  float* out = (float*)d_out;

  const size_t need = ((size_t)N_ROWS * K_DIM + (size_t)N_COLS * K_DIM) * sizeof(unsigned short);
  if (ws_size < need) {
    dim3 grid(N_COLS / 256, N_ROWS);
    fallback_kernel<<<grid, 256, 0, stream>>>(x, w, A, Bm, out);
    return;
  }

  unsigned short* xb = (unsigned short*)d_ws;
  unsigned short* wb = xb + (size_t)N_ROWS * K_DIM;

  prep_kernel<<<XBLK + WBLK, 256, 0, stream>>>(x, w, A, Bm, xb, wb);

  const int grid_gemm = (N_ROWS / 256) * (N_COLS / 256);   // 512
  gemm_bf16_r8<<<grid_gemm, 512, 0, stream>>>(xb, wb, out);
}